// Round 3
// baseline (302.424 us; speedup 1.0000x reference)
//
#include <hip/hip_runtime.h>

// Wavelet lifting net, MI355X fp32 implementation.
// Pipeline (ws use = 24 MiB only: L, Hb):
//  K1 yuv_split : x(8,3,512,512) -> L(24,256,512), Hb(24,256,512)   [n = c*8+b]
//  K2 subnet    : inout +/- subnet(in)  (fused conv1->relu->conv2)
//                 NOTE: hidden map is zero OUTSIDE [0,H)x[0,W) (conv2 SAME
//                 padding pads the hidden map with zeros, NOT conv1(halo)).
//  K3 col_split : L -> (LL,HL), Hb -> (LH,HH), written DIRECTLY into d_out
//                 at final batch2channel positions: out[b, q*3+c, :, :]
//  Stage-2/3 lifts run untransposed with spatially transposed weights,
//  in-place inside d_out (io==out per-element; conv input is a disjoint
//  plane region => race-free).

struct TensorDesc {
  const float* in;  int in_mode,  in_qb;
  const float* io;  int io_mode,  io_qb;
  float*       out; int out_mode, out_qb;
};

__device__ __forceinline__ long planeOff(int n, int mode, int qb, int HW) {
  // mode 0: plane n in a packed (24,H,W) array         (n = c*8 + b)
  // mode 1: d_out scatter: plane = b*12 + qb + c, 12 channels per batch
  int p = mode ? ((n & 7) * 12 + qb + (n >> 3)) : n;
  return (long)p * HW;
}

__device__ __forceinline__ float4 yuvmix(float4 r, float4 g, float4 b,
                                         float m0, float m1, float m2) {
  return make_float4(m0*r.x + m1*g.x + m2*b.x,
                     m0*r.y + m1*g.y + m2*b.y,
                     m0*r.z + m1*g.z + m2*b.z,
                     m0*r.w + m1*g.w + m2*b.w);
}

// ---------------- K1: rgb2yuv + even/odd row split -------------------------
__global__ __launch_bounds__(256) void k_yuv_split(
    const float* __restrict__ x, float* __restrict__ L, float* __restrict__ H) {
  int idx = blockIdx.x * 256 + threadIdx.x;   // (b:3b, h:9b, w4:7b) = 8*512*128
  int w4 = idx & 127;
  int h  = (idx >> 7) & 511;
  int b  = idx >> 16;
  const float4* xr = (const float4*)x;
  float4 r  = xr[((b*3 + 0)*512 + h)*128 + w4];
  float4 g  = xr[((b*3 + 1)*512 + h)*128 + w4];
  float4 bl = xr[((b*3 + 2)*512 + h)*128 + w4];
  float4 y0 = yuvmix(r, g, bl,  0.299f,  0.587f,  0.114f);
  float4 y1 = yuvmix(r, g, bl, -0.147f, -0.289f,  0.436f);
  float4 y2 = yuvmix(r, g, bl,  0.615f, -0.515f, -0.100f);
  float4* dst = (h & 1) ? (float4*)H : (float4*)L;
  int row = h >> 1;
  dst[((0*8 + b)*256 + row)*128 + w4] = y0;
  dst[((1*8 + b)*256 + row)*128 + w4] = y1;
  dst[((2*8 + b)*256 + row)*128 + w4] = y2;
}

// ---------------- K3: even/odd column split -> d_out (scattered) -----------
__global__ __launch_bounds__(256) void k_col_split(
    const float* __restrict__ L,  const float* __restrict__ Hb,
    float* __restrict__ out) {
  int idx = blockIdx.x * 256 + threadIdx.x;   // (which, n, r, j): 2*24*256*64
  int j = idx & 63;
  int r = (idx >> 6) & 255;
  int t = idx >> 14;            // [0, 48)
  int n = t % 24;
  int which = t / 24;
  const float4* src = (const float4*)(which ? Hb : L);
  int base = (n*256 + r)*128 + 2*j;
  float4 a = src[base];
  float4 b4 = src[base + 1];
  float4 ev = make_float4(a.x, a.z, b4.x, b4.z);   // even cols -> LL / LH
  float4 od = make_float4(a.y, a.w, b4.y, b4.w);   // odd cols  -> HL / HH
  int b = n & 7, c = n >> 3;
  int pe = b*12 + (which ? 6 : 0) + c;
  int po = b*12 + (which ? 9 : 3) + c;
  float4* o4 = (float4*)out;
  o4[(pe*256 + r)*64 + j] = ev;
  o4[(po*256 + r)*64 + j] = od;
}

// ---------------- K2: fused subnet: out = io + sign * subnet(in) -----------
// Block: 256 threads, 64x64 output tile; thread = 4x4 outputs.
// Input tile (68x68, halo 2) staged in LDS; 8x8 window per thread in regs.
// Hidden values outside the image are forced to ZERO (conv2 SAME padding).
// TRANS=1: spatially transposed 3x3 weights (for transposed-space lifts).
template<int TRANS>
__global__ __launch_bounds__(256) void k_subnet(
    TensorDesc d0, TensorDesc d1, int N,
    const float* __restrict__ W1, const float* __restrict__ B1,
    const float* __restrict__ W2, const float* __restrict__ B2,
    float sign, int IH, int IW) {
  __shared__ __align__(16) float sIn[68*68];
  int z = blockIdx.z;
  TensorDesc d = (z < N) ? d0 : d1;
  int n = (z < N) ? z : z - N;
  int HW = IH * IW;
  const float* inp  = d.in  + planeOff(n, d.in_mode,  d.in_qb,  HW);
  const float* iop  = d.io  + planeOff(n, d.io_mode,  d.io_qb,  HW);
  float*       outp = d.out + planeOff(n, d.out_mode, d.out_qb, HW);
  int x0 = blockIdx.x * 64, y0 = blockIdx.y * 64;
  int tid = threadIdx.x;

  for (int i = tid; i < 68*68; i += 256) {
    int ly = i / 68, lx = i - ly*68;
    int gy = y0 + ly - 2, gx = x0 + lx - 2;
    float v = 0.f;
    if ((unsigned)gy < (unsigned)IH && (unsigned)gx < (unsigned)IW)
      v = inp[gy*IW + gx];
    sIn[i] = v;
  }
  __syncthreads();

  int tx = tid & 15, ty = tid >> 4;
  float in_reg[8][8];
#pragma unroll
  for (int rr = 0; rr < 8; ++rr) {
    const float4* p = (const float4*)&sIn[(ty*4 + rr)*68 + tx*4];
    float4 a = p[0], b = p[1];
    in_reg[rr][0]=a.x; in_reg[rr][1]=a.y; in_reg[rr][2]=a.z; in_reg[rr][3]=a.w;
    in_reg[rr][4]=b.x; in_reg[rr][5]=b.y; in_reg[rr][6]=b.z; in_reg[rr][7]=b.w;
  }

  // hidden-map validity masks (conv2 SAME pads the HIDDEN map with zeros)
  float rowm[6], colm[6];
#pragma unroll
  for (int k = 0; k < 6; ++k) {
    rowm[k] = ((unsigned)(y0 + ty*4 + k - 1) < (unsigned)IH) ? 1.f : 0.f;
    colm[k] = ((unsigned)(x0 + tx*4 + k - 1) < (unsigned)IW) ? 1.f : 0.f;
  }

  float acc[4][4] = {{0.f,0.f,0.f,0.f},{0.f,0.f,0.f,0.f},
                     {0.f,0.f,0.f,0.f},{0.f,0.f,0.f,0.f}};

#pragma unroll 1
  for (int c = 0; c < 16; ++c) {
    float w1v[9], w2v[9];
#pragma unroll
    for (int j = 0; j < 9; ++j) {
      int jt = TRANS ? ((j % 3) * 3 + (j / 3)) : j;
      w1v[j] = W1[c*9 + jt];
      w2v[j] = W2[c*9 + jt];
    }
    float b1c = B1[c];
#pragma unroll
    for (int hy = 0; hy < 6; ++hy) {
      float h[6];
#pragma unroll
      for (int hx = 0; hx < 6; ++hx) {
        float s = b1c;
#pragma unroll
        for (int dy = 0; dy < 3; ++dy)
#pragma unroll
          for (int dx = 0; dx < 3; ++dx)
            s = fmaf(w1v[dy*3+dx], in_reg[hy+dy][hx+dx], s);
        h[hx] = fmaxf(s, 0.f) * (rowm[hy] * colm[hx]);
      }
      // conv2 contributions of this hidden row to output rows hy-2..hy
#pragma unroll
      for (int dy = 0; dy < 3; ++dy) {
        int r = hy - dy;
        if (r >= 0 && r < 4) {
#pragma unroll
          for (int cx = 0; cx < 4; ++cx)
#pragma unroll
            for (int dx = 0; dx < 3; ++dx)
              acc[r][cx] = fmaf(w2v[dy*3+dx], h[cx+dx], acc[r][cx]);
        }
      }
    }
  }

  float b2v = B2[0];
#pragma unroll
  for (int r = 0; r < 4; ++r) {
    int gy = y0 + ty*4 + r, gx = x0 + tx*4;
    float4 v = *(const float4*)&iop[gy*IW + gx];
    v.x += sign * (acc[r][0] + b2v);
    v.y += sign * (acc[r][1] + b2v);
    v.z += sign * (acc[r][2] + b2v);
    v.w += sign * (acc[r][3] + b2v);
    *(float4*)&outp[gy*IW + gx] = v;
  }
}

extern "C" void kernel_launch(void* const* d_in, const int* in_sizes, int n_in,
                              void* d_out, int out_size, void* d_ws, size_t ws_size,
                              hipStream_t stream) {
  const float* x   = (const float*)d_in[0];
  const float* Wp1 = (const float*)d_in[1];
  const float* bp1 = (const float*)d_in[2];
  const float* Wp2 = (const float*)d_in[3];
  const float* bp2 = (const float*)d_in[4];
  const float* Wu1 = (const float*)d_in[5];
  const float* bu1 = (const float*)d_in[6];
  const float* Wu2 = (const float*)d_in[7];
  const float* bu2 = (const float*)d_in[8];
  float* out = (float*)d_out;
  float* ws  = (float*)d_ws;

  const int P1 = 24*256*512;   // stage-1 plane set size (floats)
  float* L   = ws;             // 12 MiB
  float* Hb  = L + P1;         // 12 MiB  (total ws use = 24 MiB)

  // K1: rgb2yuv + row split
  k_yuv_split<<<2048, 256, 0, stream>>>(x, L, Hb);

  // Lift 1 (rows): Hb -= subnet_p(L);  L += subnet_u(Hb)
  TensorDesc s1a = { L,0,0,  Hb,0,0, Hb,0,0 };
  k_subnet<0><<<dim3(8,4,24), 256, 0, stream>>>(s1a, s1a, 24,
      Wp1, bp1, Wp2, bp2, -1.f, 256, 512);
  TensorDesc s1b = { Hb,0,0, L,0,0,  L,0,0 };
  k_subnet<0><<<dim3(8,4,24), 256, 0, stream>>>(s1b, s1b, 24,
      Wu1, bu1, Wu2, bu2, +1.f, 256, 512);

  // K3: column split directly into d_out final positions
  //   q regions: 0=LL 1=HL 2=LH 3=HH ; qb = q*3
  k_col_split<<<3072, 256, 0, stream>>>(L, Hb, out);

  // Lifts 2&3 (transposed space, transposed weights), in-place in d_out:
  // step a: HL -= subnetT_p(LL)  [qb3 -= p(qb0)] ; HH -= subnetT_p(LH) [qb9 -= p(qb6)]
  TensorDesc s2a0 = { out,1,0, out,1,3, out,1,3 };
  TensorDesc s2a1 = { out,1,6, out,1,9, out,1,9 };
  k_subnet<1><<<dim3(4,4,48), 256, 0, stream>>>(s2a0, s2a1, 24,
      Wp1, bp1, Wp2, bp2, -1.f, 256, 256);
  // step b: LL += subnetT_u(HL) [qb0 += u(qb3)] ; LH += subnetT_u(HH) [qb6 += u(qb9)]
  TensorDesc s2b0 = { out,1,3, out,1,0, out,1,0 };
  TensorDesc s2b1 = { out,1,9, out,1,6, out,1,6 };
  k_subnet<1><<<dim3(4,4,48), 256, 0, stream>>>(s2b0, s2b1, 24,
      Wu1, bu1, Wu2, bu2, +1.f, 256, 256);
}

// Round 4
// 291.821 us; speedup vs baseline: 1.0363x; 1.0363x over previous
//
#include <hip/hip_runtime.h>

// Wavelet lifting net, MI355X fp32 — 4 fused launches.
//  S1P (MODE0): in = YUV(x) even rows (on the fly, halo in LDS); io = YUV(x)
//               odd rows; out = Hb' (ws). Also writes staged L tile to ws.
//  S1U (MODE1): in = Hb' (ws, halo); io = L (ws); out = L' (ws, in-place).
//  S2P (MODE2): in = even cols of L'/Hb' (de-interleaved in staging);
//               io = odd cols; out = d_out q1/q3 (HL'/HH'). Transposed wts.
//  S2U (MODE3): in = d_out q1/q3 (halo); io = even cols of L'/Hb';
//               out = d_out q0/q2 (LL'/LH'). Transposed wts.
// Hidden map is zero OUTSIDE the image (conv2 SAME pads the hidden map).
// Weights cached in LDS, double-buffered prefetch in the channel loop.

#define P1 (24*256*512)

template<int MODE>
__global__ __launch_bounds__(256, 3) void k_subnet(
    const float* __restrict__ xp, float* __restrict__ ws, float* __restrict__ outp,
    const float* __restrict__ W1, const float* __restrict__ B1,
    const float* __restrict__ W2, const float* __restrict__ B2)
{
  constexpr int  IW    = (MODE <= 1) ? 512 : 256;
  constexpr int  HW    = 256 * IW;
  constexpr float sign = (MODE == 0 || MODE == 2) ? -1.f : 1.f;
  constexpr int  TRANS = (MODE >= 2) ? 1 : 0;

  __shared__ __align__(16) float sIn[68*68];
  __shared__ __align__(16) float sW[16*24];

  const int z     = blockIdx.z;
  const int n     = (MODE >= 2) ? (z % 24) : z;
  const int which = (MODE >= 2) ? (z / 24) : 0;
  const int c_ = n >> 3, b_ = n & 7;
  const int x0 = blockIdx.x * 64, y0 = blockIdx.y * 64;
  const int tid = threadIdx.x;

  float* Lw = ws;                 // L / L'
  float* Hw = ws + P1;            // Hb'

  // ---- weights -> LDS (transposed 3x3 if TRANS) ----
  for (int i = tid; i < 16*24; i += 256) {
    int cc = i / 24, j = i - cc*24;
    float v = 0.f;
    if (j < 9)                  { int jt = TRANS ? ((j%3)*3 + j/3) : j; v = W1[cc*9 + jt]; }
    else if (j >= 12 && j < 21) { int k = j - 12; int jt = TRANS ? ((k%3)*3 + k/3) : k; v = W2[cc*9 + jt]; }
    else if (j == 21)           v = B1[cc];
    sW[i] = v;
  }

  // ---- input staging (68x68 with halo 2) ----
  float m0 = 0.f, m1 = 0.f, m2 = 0.f;
  if (MODE == 0) {
    m0 = (c_==0) ? 0.299f : ((c_==1) ? -0.147f :  0.615f);
    m1 = (c_==0) ? 0.587f : ((c_==1) ? -0.289f : -0.515f);
    m2 = (c_==0) ? 0.114f : ((c_==1) ?  0.436f : -0.100f);
  }
  for (int i = tid; i < 68*68; i += 256) {
    int ly = i / 68, lx = i - ly*68;
    int gy = y0 + ly - 2, gx = x0 + lx - 2;
    float v = 0.f;
    if ((unsigned)gy < 256u && (unsigned)gx < (unsigned)IW) {
      if (MODE == 0) {
        const float* xb = xp + ((long)b_*3*512 + 2*gy)*512 + gx;
        v = m0*xb[0] + m1*xb[512*512] + m2*xb[2*512*512];
      } else if (MODE == 1) {
        v = Hw[(long)n*HW + gy*IW + gx];
      } else if (MODE == 2) {
        const float* src = (which ? Hw : Lw) + (long)n*(256*512);
        v = src[gy*512 + 2*gx];
      } else {
        const float* src = outp + (long)(b_*12 + (which?9:3) + c_)*(256*256);
        v = src[gy*256 + gx];
      }
    }
    sIn[i] = v;
  }
  __syncthreads();

  const int tx = tid & 15, ty = tid >> 4;
  const int oy = y0 + ty*4, ox = x0 + tx*4;

  // ---- MODE0: write staged L interior to ws ----
  if (MODE == 0) {
    float* Lp = Lw + (long)n*HW;
#pragma unroll
    for (int r = 0; r < 4; ++r) {
      const int base = (ty*4 + r + 2)*68 + tx*4 + 2;
      float4 v = make_float4(sIn[base], sIn[base+1], sIn[base+2], sIn[base+3]);
      *(float4*)&Lp[(oy + r)*IW + ox] = v;
    }
  }

  // ---- io prefetch (4 rows of float4) ----
  float4 iov[4];
  if (MODE == 0) {
#pragma unroll
    for (int r = 0; r < 4; ++r) {
      const float* xb = xp + ((long)b_*3*512 + (2*(oy+r)+1))*512 + ox;
      float4 rr = *(const float4*)&xb[0];
      float4 gg = *(const float4*)&xb[512*512];
      float4 bb = *(const float4*)&xb[2*512*512];
      iov[r] = make_float4(m0*rr.x + m1*gg.x + m2*bb.x,
                           m0*rr.y + m1*gg.y + m2*bb.y,
                           m0*rr.z + m1*gg.z + m2*bb.z,
                           m0*rr.w + m1*gg.w + m2*bb.w);
    }
  } else if (MODE == 1) {
    const float* src = Lw + (long)n*HW;
#pragma unroll
    for (int r = 0; r < 4; ++r) iov[r] = *(const float4*)&src[(oy+r)*IW + ox];
  } else if (MODE == 2) {
    const float* src = (which ? Hw : Lw) + (long)n*(256*512);
#pragma unroll
    for (int r = 0; r < 4; ++r) {
      float4 a = *(const float4*)&src[(oy+r)*512 + 2*ox];
      float4 b = *(const float4*)&src[(oy+r)*512 + 2*ox + 4];
      iov[r] = make_float4(a.y, a.w, b.y, b.w);        // odd cols
    }
  } else {
    const float* src = (which ? Hw : Lw) + (long)n*(256*512);
#pragma unroll
    for (int r = 0; r < 4; ++r) {
      float4 a = *(const float4*)&src[(oy+r)*512 + 2*ox];
      float4 b = *(const float4*)&src[(oy+r)*512 + 2*ox + 4];
      iov[r] = make_float4(a.x, a.z, b.x, b.z);        // even cols
    }
  }
  float b2 = B2[0];

  // ---- 8x8 input window into registers ----
  float in_reg[8][8];
#pragma unroll
  for (int rr = 0; rr < 8; ++rr) {
    const float4* p = (const float4*)&sIn[(ty*4 + rr)*68 + tx*4];
    float4 a = p[0], b = p[1];
    in_reg[rr][0]=a.x; in_reg[rr][1]=a.y; in_reg[rr][2]=a.z; in_reg[rr][3]=a.w;
    in_reg[rr][4]=b.x; in_reg[rr][5]=b.y; in_reg[rr][6]=b.z; in_reg[rr][7]=b.w;
  }

  // hidden-map validity (conv2 SAME pads hidden map with zeros)
  bool  rowv[6];
  float colm[6];
#pragma unroll
  for (int k = 0; k < 6; ++k) {
    rowv[k] = ((unsigned)(oy + k - 1) < 256u);
    colm[k] = ((unsigned)(ox + k - 1) < (unsigned)IW) ? 1.f : 0.f;
  }

  // ---- channel loop, weights double-buffered from LDS ----
  auto ldsW = [&](int cc, float* w) {
    const float4* p = (const float4*)&sW[cc*24];
    float4 q0=p[0], q1=p[1], q2=p[2], q3=p[3], q4=p[4], q5=p[5];
    w[0]=q0.x; w[1]=q0.y; w[2]=q0.z; w[3]=q0.w;
    w[4]=q1.x; w[5]=q1.y; w[6]=q1.z; w[7]=q1.w;
    w[8]=q2.x;
    w[9]=q3.x; w[10]=q3.y; w[11]=q3.z; w[12]=q3.w;
    w[13]=q4.x; w[14]=q4.y; w[15]=q4.z; w[16]=q4.w;
    w[17]=q5.x;
    w[18]=q5.y;   // b1
  };

  float acc[4][4] = {{0,0,0,0},{0,0,0,0},{0,0,0,0},{0,0,0,0}};
  float wcur[19];
  ldsW(0, wcur);

#pragma unroll 1
  for (int c = 0; c < 16; ++c) {
    float wnxt[19];
    ldsW((c+1) & 15, wnxt);

    float b1r[6];
#pragma unroll
    for (int k = 0; k < 6; ++k) b1r[k] = rowv[k] ? wcur[18] : -3.0e38f;

#pragma unroll
    for (int hy = 0; hy < 6; ++hy) {
      float h[6];
#pragma unroll
      for (int hx = 0; hx < 6; ++hx) {
        float s = b1r[hy];
#pragma unroll
        for (int dy = 0; dy < 3; ++dy)
#pragma unroll
          for (int dx = 0; dx < 3; ++dx)
            s = fmaf(wcur[dy*3+dx], in_reg[hy+dy][hx+dx], s);
        h[hx] = fmaxf(s, 0.f) * colm[hx];
      }
#pragma unroll
      for (int dy = 0; dy < 3; ++dy) {
        int r = hy - dy;
        if (r >= 0 && r < 4) {
#pragma unroll
          for (int cx = 0; cx < 4; ++cx)
#pragma unroll
            for (int dx = 0; dx < 3; ++dx)
              acc[r][cx] = fmaf(wcur[9 + dy*3 + dx], h[cx+dx], acc[r][cx]);
        }
      }
    }
#pragma unroll
    for (int k = 0; k < 19; ++k) wcur[k] = wnxt[k];
  }

  // ---- epilogue ----
  float* dst;
  if      (MODE == 0) dst = Hw + (long)n*HW;
  else if (MODE == 1) dst = Lw + (long)n*HW;
  else if (MODE == 2) dst = outp + (long)(b_*12 + (which?9:3) + c_)*(256*256);
  else                dst = outp + (long)(b_*12 + (which?6:0) + c_)*(256*256);

#pragma unroll
  for (int r = 0; r < 4; ++r) {
    float4 v;
    v.x = iov[r].x + sign * (acc[r][0] + b2);
    v.y = iov[r].y + sign * (acc[r][1] + b2);
    v.z = iov[r].z + sign * (acc[r][2] + b2);
    v.w = iov[r].w + sign * (acc[r][3] + b2);
    *(float4*)&dst[(oy + r)*IW + ox] = v;
  }
}

extern "C" void kernel_launch(void* const* d_in, const int* in_sizes, int n_in,
                              void* d_out, int out_size, void* d_ws, size_t ws_size,
                              hipStream_t stream) {
  const float* x   = (const float*)d_in[0];
  const float* Wp1 = (const float*)d_in[1];
  const float* bp1 = (const float*)d_in[2];
  const float* Wp2 = (const float*)d_in[3];
  const float* bp2 = (const float*)d_in[4];
  const float* Wu1 = (const float*)d_in[5];
  const float* bu1 = (const float*)d_in[6];
  const float* Wu2 = (const float*)d_in[7];
  const float* bu2 = (const float*)d_in[8];
  float* out = (float*)d_out;
  float* ws  = (float*)d_ws;

  // S1P: Hb' = Hb - p(L); also materializes L in ws
  k_subnet<0><<<dim3(8,4,24), 256, 0, stream>>>(x, ws, out, Wp1, bp1, Wp2, bp2);
  // S1U: L' = L + u(Hb')
  k_subnet<1><<<dim3(8,4,24), 256, 0, stream>>>(x, ws, out, Wu1, bu1, Wu2, bu2);
  // S2P: HL' = HL - pT(LL) -> q1 ; HH' = HH - pT(LH) -> q3
  k_subnet<2><<<dim3(4,4,48), 256, 0, stream>>>(x, ws, out, Wp1, bp1, Wp2, bp2);
  // S2U: LL' = LL + uT(HL') -> q0 ; LH' = LH + uT(HH') -> q2
  k_subnet<3><<<dim3(4,4,48), 256, 0, stream>>>(x, ws, out, Wu1, bu1, Wu2, bu2);
}

// Round 6
// 260.577 us; speedup vs baseline: 1.1606x; 1.1199x over previous
//
#include <hip/hip_runtime.h>
#include <hip/hip_fp16.h>

// Wavelet lifting net, MI355X — 4 fused launches, packed-f16 inner math.
//  MODE0: in = YUV(x) even rows (on the fly); io = YUV(x) odd rows;
//         out = Hb' (ws). Side-writes L (f32) to ws during staging.
//  MODE1: in = Hb' (halo); io = L; out = L' (in-place in ws).
//  MODE2: in = even cols of L'/Hb'; io = odd cols; out = d_out q1/q3. (T wts)
//  MODE3: in = d_out q1/q3; io = even cols of L'/Hb'; out = q0/q2.   (T wts)
// Hidden map is zero OUTSIDE the image (conv2 SAME pads the hidden map):
// row-invalid folded into bias=-60000 (relu->0), col mask on edge blocks.
// Compute: v_pk_fma_f16 pairs; conv2 accumulated f16 per 4-ch group, folded
// to fp32 every 4 channels. relu via inline-asm v_pk_max_f16 (no __hmax2 in
// ROCm 7.2 headers).

#define P1 (24*256*512)

__device__ __forceinline__ __half2 oddpair(__half2 a, __half2 b) {
  // (a.hi, b.lo) in one v_alignbit
  unsigned ua = __builtin_bit_cast(unsigned, a), ub = __builtin_bit_cast(unsigned, b);
  unsigned r = __builtin_amdgcn_alignbit(ub, ua, 16);
  return __builtin_bit_cast(__half2, r);
}

__device__ __forceinline__ __half2 relu2(__half2 s) {
  unsigned u = __builtin_bit_cast(unsigned, s), r;
  asm("v_pk_max_f16 %0, %1, 0" : "=v"(r) : "v"(u));
  return __builtin_bit_cast(__half2, r);
}

template<int MODE>
__global__ __launch_bounds__(256, 4) void k_subnet(
    const float* __restrict__ xp, float* __restrict__ ws, float* __restrict__ outp,
    const float* __restrict__ W1, const float* __restrict__ B1,
    const float* __restrict__ W2, const float* __restrict__ B2)
{
  constexpr int  IW    = (MODE <= 1) ? 512 : 256;
  constexpr int  HW    = 256 * IW;
  constexpr float sign = (MODE == 0 || MODE == 2) ? -1.f : 1.f;
  constexpr int  TRANS = (MODE >= 2) ? 1 : 0;

  __shared__ __align__(16) __half2 sW[16*20];   // per ch: w1[0..8], b1, w2[10..18], pad
  __shared__ __align__(16) __half  sIn[36*70];  // 64x32 tile + halo 2, stride 70

  const int z     = blockIdx.z;
  const int n     = (MODE >= 2) ? (z % 24) : z;
  const int which = (MODE >= 2) ? (z / 24) : 0;
  const int c_ = n >> 3, b_ = n & 7;
  const int x0 = blockIdx.x * 64, y0 = blockIdx.y * 32;
  const int tid = threadIdx.x;
  float* Lw = ws;
  float* Hw = ws + P1;

  // ---- weights -> LDS as broadcast half2 (transposed 3x3 if TRANS) ----
  for (int i = tid; i < 320; i += 256) {
    int cc = i / 20, j = i - cc*20;
    float v = 0.f;
    if (j < 9)       { int jt = TRANS ? ((j%3)*3 + j/3) : j; v = W1[cc*9 + jt]; }
    else if (j == 9) v = B1[cc];
    else if (j < 19) { int k = j - 10; int jt = TRANS ? ((k%3)*3 + k/3) : k; v = W2[cc*9 + jt]; }
    __half h = __float2half(v);
    sW[i] = __halves2half2(h, h);
  }

  // ---- input staging (68x36 halo-2 window) ----
  float m0 = 0.f, m1 = 0.f, m2 = 0.f;
  if (MODE == 0) {
    m0 = (c_==0) ? 0.299f : ((c_==1) ? -0.147f :  0.615f);
    m1 = (c_==0) ? 0.587f : ((c_==1) ? -0.289f : -0.515f);
    m2 = (c_==0) ? 0.114f : ((c_==1) ?  0.436f : -0.100f);
  }
  for (int i = tid; i < 36*68; i += 256) {
    int ly = i / 68, lx = i - ly*68;
    int gy = y0 + ly - 2, gx = x0 + lx - 2;
    float v = 0.f;
    if ((unsigned)gy < 256u && (unsigned)gx < (unsigned)IW) {
      if (MODE == 0) {
        const float* xb = xp + ((long)b_*3*512 + 2*gy)*512 + gx;
        v = m0*xb[0] + m1*xb[262144] + m2*xb[524288];
        Lw[(long)n*HW + gy*IW + gx] = v;            // side-product L (f32)
      } else if (MODE == 1) {
        v = Hw[(long)n*HW + gy*IW + gx];
      } else if (MODE == 2) {
        const float* s = (which ? Hw : Lw) + (long)n*(256*512);
        v = s[gy*512 + 2*gx];                        // even cols
      } else {
        const float* s = outp + (long)(b_*12 + (which?9:3) + c_)*65536;
        v = s[gy*256 + gx];
      }
    }
    sIn[ly*70 + lx] = __float2half(v);
  }
  __syncthreads();

  const int tx = tid & 15, ty = tid >> 4;        // 16 x 16 threads
  const int oy = y0 + ty*2, ox = x0 + tx*4;      // 4x2 outputs per thread

  // ---- 8x6 input window as half2 pairs, both alignments ----
  __half2 E[6][4], O[6][3];
#pragma unroll
  for (int r = 0; r < 6; ++r) {
    const __half2* row = (const __half2*)&sIn[(ty*2 + r)*70 + tx*4];
    E[r][0] = row[0]; E[r][1] = row[1]; E[r][2] = row[2]; E[r][3] = row[3];
    O[r][0] = oddpair(E[r][0], E[r][1]);
    O[r][1] = oddpair(E[r][1], E[r][2]);
    O[r][2] = oddpair(E[r][2], E[r][3]);
  }

  // ---- hidden-map validity ----
  const bool edgex = (x0 == 0) || (x0 + 64 == IW);
  bool rowok[4];
#pragma unroll
  for (int k = 0; k < 4; ++k) rowok[k] = ((unsigned)(oy - 1 + k) < 256u);
  __half2 mE[3];
  if (edgex) {
#pragma unroll
    for (int p = 0; p < 3; ++p) {
      float a = ((unsigned)(ox - 1 + 2*p) < (unsigned)IW) ? 1.f : 0.f;
      float b = ((unsigned)(ox     + 2*p) < (unsigned)IW) ? 1.f : 0.f;
      mE[p] = __halves2half2(__float2half(a), __float2half(b));
    }
  }

  const __half2 zero2 = __halves2half2(__float2half(0.f), __float2half(0.f));
  const __half2 negb  = __halves2half2(__float2half(-60000.f), __float2half(-60000.f));

  float   ACCF[2][4] = {{0,0,0,0},{0,0,0,0}};
  __half2 ACC2[2][2] = {{zero2, zero2},{zero2, zero2}};

#pragma unroll 1
  for (int c = 0; c < 16; ++c) {
    __half2 wv[20];
    const float4* wq = (const float4*)&sW[c*20];
#pragma unroll
    for (int q = 0; q < 5; ++q) {
      float4 f = wq[q];
      __half2 ph[4];
      ph[0] = __builtin_bit_cast(__half2, f.x);
      ph[1] = __builtin_bit_cast(__half2, f.y);
      ph[2] = __builtin_bit_cast(__half2, f.z);
      ph[3] = __builtin_bit_cast(__half2, f.w);
      wv[4*q+0] = ph[0]; wv[4*q+1] = ph[1]; wv[4*q+2] = ph[2]; wv[4*q+3] = ph[3];
    }
    __half2 bias[4];
#pragma unroll
    for (int k = 0; k < 4; ++k) bias[k] = rowok[k] ? wv[9] : negb;

#pragma unroll
    for (int k = 0; k < 4; ++k) {
      __half2 HE[3];
#pragma unroll
      for (int p = 0; p < 3; ++p) {
        __half2 s = bias[k];
#pragma unroll
        for (int dy = 0; dy < 3; ++dy) {
          s = __hfma2(wv[dy*3+0], E[k+dy][p],   s);
          s = __hfma2(wv[dy*3+1], O[k+dy][p],   s);
          s = __hfma2(wv[dy*3+2], E[k+dy][p+1], s);
        }
        HE[p] = relu2(s);
      }
      if (edgex) {
        HE[0] = __hmul2(HE[0], mE[0]);
        HE[1] = __hmul2(HE[1], mE[1]);
        HE[2] = __hmul2(HE[2], mE[2]);
      }
      __half2 HO0 = oddpair(HE[0], HE[1]);
      __half2 HO1 = oddpair(HE[1], HE[2]);
#pragma unroll
      for (int dy = 0; dy < 3; ++dy) {
        const int r = k - dy;
        if (r == 0 || r == 1) {
#pragma unroll
          for (int cp = 0; cp < 2; ++cp) {
            __half2 a = ACC2[r][cp];
            a = __hfma2(wv[10+dy*3+0], HE[cp],          a);
            a = __hfma2(wv[10+dy*3+1], (cp ? HO1 : HO0), a);
            a = __hfma2(wv[10+dy*3+2], HE[cp+1],        a);
            ACC2[r][cp] = a;
          }
        }
      }
    }
    if ((c & 3) == 3) {      // fold f16 group accumulator into fp32
#pragma unroll
      for (int r = 0; r < 2; ++r)
#pragma unroll
        for (int cp = 0; cp < 2; ++cp) {
          ACCF[r][2*cp]   += __low2float(ACC2[r][cp]);
          ACCF[r][2*cp+1] += __high2float(ACC2[r][cp]);
          ACC2[r][cp] = zero2;
        }
    }
  }

  // ---- epilogue: out = io + sign*(acc + b2) ----
  const float b2 = B2[0];
  float4 iov[2];
  if (MODE == 0) {
#pragma unroll
    for (int r = 0; r < 2; ++r) {
      const float* xb = xp + ((long)b_*3*512 + (2*(oy+r)+1))*512 + ox;
      float4 rr = *(const float4*)&xb[0];
      float4 gg = *(const float4*)&xb[262144];
      float4 bb = *(const float4*)&xb[524288];
      iov[r] = make_float4(m0*rr.x + m1*gg.x + m2*bb.x,
                           m0*rr.y + m1*gg.y + m2*bb.y,
                           m0*rr.z + m1*gg.z + m2*bb.z,
                           m0*rr.w + m1*gg.w + m2*bb.w);
    }
  } else if (MODE == 1) {
    const float* s = Lw + (long)n*HW;
#pragma unroll
    for (int r = 0; r < 2; ++r) iov[r] = *(const float4*)&s[(oy+r)*IW + ox];
  } else {
    const float* s = (which ? Hw : Lw) + (long)n*(256*512);
#pragma unroll
    for (int r = 0; r < 2; ++r) {
      float4 a = *(const float4*)&s[(oy+r)*512 + 2*ox];
      float4 b = *(const float4*)&s[(oy+r)*512 + 2*ox + 4];
      iov[r] = (MODE == 2) ? make_float4(a.y, a.w, b.y, b.w)    // odd cols
                           : make_float4(a.x, a.z, b.x, b.z);   // even cols
    }
  }

  float* dst;
  if      (MODE == 0) dst = Hw + (long)n*HW;
  else if (MODE == 1) dst = Lw + (long)n*HW;
  else if (MODE == 2) dst = outp + (long)(b_*12 + (which?9:3) + c_)*65536;
  else                dst = outp + (long)(b_*12 + (which?6:0) + c_)*65536;

#pragma unroll
  for (int r = 0; r < 2; ++r) {
    float4 v;
    v.x = iov[r].x + sign * (ACCF[r][0] + b2);
    v.y = iov[r].y + sign * (ACCF[r][1] + b2);
    v.z = iov[r].z + sign * (ACCF[r][2] + b2);
    v.w = iov[r].w + sign * (ACCF[r][3] + b2);
    *(float4*)&dst[(oy + r)*IW + ox] = v;
  }
}

extern "C" void kernel_launch(void* const* d_in, const int* in_sizes, int n_in,
                              void* d_out, int out_size, void* d_ws, size_t ws_size,
                              hipStream_t stream) {
  const float* x   = (const float*)d_in[0];
  const float* Wp1 = (const float*)d_in[1];
  const float* bp1 = (const float*)d_in[2];
  const float* Wp2 = (const float*)d_in[3];
  const float* bp2 = (const float*)d_in[4];
  const float* Wu1 = (const float*)d_in[5];
  const float* bu1 = (const float*)d_in[6];
  const float* Wu2 = (const float*)d_in[7];
  const float* bu2 = (const float*)d_in[8];
  float* out = (float*)d_out;
  float* ws  = (float*)d_ws;

  // S1P: Hb' = Hb - p(L); materializes L
  k_subnet<0><<<dim3(8,8,24), 256, 0, stream>>>(x, ws, out, Wp1, bp1, Wp2, bp2);
  // S1U: L' = L + u(Hb')
  k_subnet<1><<<dim3(8,8,24), 256, 0, stream>>>(x, ws, out, Wu1, bu1, Wu2, bu2);
  // S2P: HL' = HL - pT(LL) -> q1 ; HH' = HH - pT(LH) -> q3
  k_subnet<2><<<dim3(4,8,48), 256, 0, stream>>>(x, ws, out, Wp1, bp1, Wp2, bp2);
  // S2U: LL' = LL + uT(HL') -> q0 ; LH' = LH + uT(HH') -> q2
  k_subnet<3><<<dim3(4,8,48), 256, 0, stream>>>(x, ws, out, Wu1, bu1, Wu2, bu2);
}

// Round 8
// 245.183 us; speedup vs baseline: 1.2335x; 1.0628x over previous
//
#include <hip/hip_runtime.h>
#include <hip/hip_fp16.h>

// Wavelet lifting net, MI355X — 4 launches, packed-f16 math, 4x4 out/thread.
//  MODE0: in = YUV(x) even rows (on the fly, side-writes L); io = YUV odd;
//         dst = Hb' (ws).
//  MODE1: in = Hb' (halo); io = L; dst = L' (in-place in ws).
//  MODE2: in = even cols of L'/Hb'; io = odd cols; dst = d_out q1/q3. (T wts)
//  MODE3: in = d_out q1/q3; io = even cols; dst = d_out q0/q2.        (T wts)
// Hidden map is zero OUTSIDE the image (conv2 SAME pads hidden map):
// row-invalid folded into bias=-60000 (relu->0), col mask on edge blocks.
// conv2 accumulated f16 per 4-channel group, folded to fp32.

#define P1 (24*256*512)

__device__ __forceinline__ __half2 oddpair(__half2 a, __half2 b) {
  unsigned ua = __builtin_bit_cast(unsigned, a), ub = __builtin_bit_cast(unsigned, b);
  unsigned r = __builtin_amdgcn_alignbit(ub, ua, 16);
  return __builtin_bit_cast(__half2, r);
}

__device__ __forceinline__ __half2 relu2(__half2 s) {
  unsigned u = __builtin_bit_cast(unsigned, s), r;
  asm("v_pk_max_f16 %0, %1, 0" : "=v"(r) : "v"(u));
  return __builtin_bit_cast(__half2, r);
}

template<int MODE>
__global__ __launch_bounds__(256, 3) void k_subnet(
    const float* __restrict__ xp, float* __restrict__ ws, float* __restrict__ outp,
    const float* __restrict__ W1, const float* __restrict__ B1,
    const float* __restrict__ W2, const float* __restrict__ B2)
{
  constexpr int  IW    = (MODE <= 1) ? 512 : 256;
  constexpr int  HW    = 256 * IW;
  constexpr float sign = (MODE == 0 || MODE == 2) ? -1.f : 1.f;
  constexpr int  TRANS = (MODE >= 2) ? 1 : 0;

  __shared__ __align__(16) __half2 sW[16*20];   // per ch: w1[0..8], b1, w2[10..18], pad
  __shared__ __align__(16) __half  sIn[68*72];  // 64x64 tile + halo 2, stride 72

  const int z     = blockIdx.z;
  const int n     = (MODE >= 2) ? (z % 24) : z;
  const int which = (MODE >= 2) ? (z / 24) : 0;
  const int c_ = n >> 3, b_ = n & 7;
  const int x0 = blockIdx.x * 64, y0 = blockIdx.y * 64;
  const int tid = threadIdx.x;
  float* Lw = ws;
  float* Hw = ws + P1;

  // ---- weights -> LDS as broadcast half2 (transposed 3x3 if TRANS) ----
  for (int i = tid; i < 320; i += 256) {
    int cc = i / 20, j = i - cc*20;
    float v = 0.f;
    if (j < 9)       { int jt = TRANS ? ((j%3)*3 + j/3) : j; v = W1[cc*9 + jt]; }
    else if (j == 9) v = B1[cc];
    else if (j < 19) { int k = j - 10; int jt = TRANS ? ((k%3)*3 + k/3) : k; v = W2[cc*9 + jt]; }
    __half h = __float2half(v);
    sW[i] = __halves2half2(h, h);
  }

  // ---- input staging (68x68 halo-2 window) ----
  float m0 = 0.f, m1 = 0.f, m2 = 0.f;
  if (MODE == 0) {
    m0 = (c_==0) ? 0.299f : ((c_==1) ? -0.147f :  0.615f);
    m1 = (c_==0) ? 0.587f : ((c_==1) ? -0.289f : -0.515f);
    m2 = (c_==0) ? 0.114f : ((c_==1) ?  0.436f : -0.100f);
  }
  for (int i = tid; i < 68*68; i += 256) {
    int ly = i / 68, lx = i - ly*68;
    int gy = y0 + ly - 2, gx = x0 + lx - 2;
    float v = 0.f;
    if ((unsigned)gy < 256u && (unsigned)gx < (unsigned)IW) {
      if (MODE == 0) {
        const float* xb = xp + ((long)b_*3*512 + 2*gy)*512 + gx;
        v = m0*xb[0] + m1*xb[262144] + m2*xb[524288];
        Lw[(long)n*HW + gy*IW + gx] = v;            // side-product L (f32)
      } else if (MODE == 1) {
        v = Hw[(long)n*HW + gy*IW + gx];
      } else if (MODE == 2) {
        const float* s = (which ? Hw : Lw) + (long)n*(256*512);
        v = s[gy*512 + 2*gx];                        // even cols
      } else {
        const float* s = outp + (long)(b_*12 + (which?9:3) + c_)*65536;
        v = s[gy*256 + gx];
      }
    }
    sIn[ly*72 + lx] = __float2half(v);
  }
  __syncthreads();

  const int tx = tid & 15, ty = tid >> 4;        // 16 x 16 threads
  const int oy = y0 + ty*4, ox = x0 + tx*4;      // 4x4 outputs per thread

  // ---- 8x8 input window as half2 pairs, both alignments ----
  __half2 E[8][4], O[8][3];
#pragma unroll
  for (int r = 0; r < 8; ++r) {
    const __half2* row = (const __half2*)&sIn[(ty*4 + r)*72 + tx*4];
    E[r][0] = row[0]; E[r][1] = row[1]; E[r][2] = row[2]; E[r][3] = row[3];
    O[r][0] = oddpair(E[r][0], E[r][1]);
    O[r][1] = oddpair(E[r][1], E[r][2]);
    O[r][2] = oddpair(E[r][2], E[r][3]);
  }

  // ---- hidden-map validity ----
  const bool edgex = (x0 == 0) || (x0 + 64 == IW);
  bool rowok[6];
#pragma unroll
  for (int k = 0; k < 6; ++k) rowok[k] = ((unsigned)(oy - 1 + k) < 256u);
  __half2 mE[3];
  if (edgex) {
#pragma unroll
    for (int p = 0; p < 3; ++p) {
      float a = ((unsigned)(ox - 1 + 2*p) < (unsigned)IW) ? 1.f : 0.f;
      float b = ((unsigned)(ox     + 2*p) < (unsigned)IW) ? 1.f : 0.f;
      mE[p] = __halves2half2(__float2half(a), __float2half(b));
    }
  }

  const __half2 zero2 = __builtin_bit_cast(__half2, 0u);
  const __half2 negb  = __halves2half2(__float2half(-60000.f), __float2half(-60000.f));

  float   ACCF[4][4] = {{0,0,0,0},{0,0,0,0},{0,0,0,0},{0,0,0,0}};
  __half2 ACC2[4][2] = {{zero2,zero2},{zero2,zero2},{zero2,zero2},{zero2,zero2}};

#pragma unroll 1
  for (int c = 0; c < 16; ++c) {
    __half2 wv[20];
    const float4* wq = (const float4*)&sW[c*20];
#pragma unroll
    for (int q = 0; q < 5; ++q) {
      float4 f = wq[q];
      wv[4*q+0] = __builtin_bit_cast(__half2, f.x);
      wv[4*q+1] = __builtin_bit_cast(__half2, f.y);
      wv[4*q+2] = __builtin_bit_cast(__half2, f.z);
      wv[4*q+3] = __builtin_bit_cast(__half2, f.w);
    }
    __half2 bias[6];
#pragma unroll
    for (int k = 0; k < 6; ++k) bias[k] = rowok[k] ? wv[9] : negb;

#pragma unroll
    for (int kk = 0; kk < 6; ++kk) {
      __half2 HE[3];
#pragma unroll
      for (int p = 0; p < 3; ++p) {
        __half2 hs = bias[kk];
#pragma unroll
        for (int dy = 0; dy < 3; ++dy) {
          hs = __hfma2(wv[dy*3+0], E[kk+dy][p],   hs);
          hs = __hfma2(wv[dy*3+1], O[kk+dy][p],   hs);
          hs = __hfma2(wv[dy*3+2], E[kk+dy][p+1], hs);
        }
        HE[p] = relu2(hs);
      }
      if (edgex) {
        HE[0] = __hmul2(HE[0], mE[0]);
        HE[1] = __hmul2(HE[1], mE[1]);
        HE[2] = __hmul2(HE[2], mE[2]);
      }
      __half2 HO0 = oddpair(HE[0], HE[1]);
      __half2 HO1 = oddpair(HE[1], HE[2]);
#pragma unroll
      for (int dy = 0; dy < 3; ++dy) {
        const int r = kk - dy;
        if (r >= 0 && r < 4) {
#pragma unroll
          for (int cp = 0; cp < 2; ++cp) {
            __half2 a = ACC2[r][cp];
            a = __hfma2(wv[10+dy*3+0], HE[cp],           a);
            a = __hfma2(wv[10+dy*3+1], (cp ? HO1 : HO0), a);
            a = __hfma2(wv[10+dy*3+2], HE[cp+1],         a);
            ACC2[r][cp] = a;
          }
        }
      }
    }
    if ((c & 3) == 3) {      // fold f16 group accumulator into fp32
#pragma unroll
      for (int r = 0; r < 4; ++r)
#pragma unroll
        for (int cp = 0; cp < 2; ++cp) {
          ACCF[r][2*cp]   += __low2float(ACC2[r][cp]);
          ACCF[r][2*cp+1] += __high2float(ACC2[r][cp]);
          ACC2[r][cp] = zero2;
        }
    }
  }

  // ---- epilogue: out = io + sign*(acc + b2) ----
  const float b2 = B2[0];
  float4 iov[4];
  if (MODE == 0) {
#pragma unroll
    for (int r = 0; r < 4; ++r) {
      const float* xb = xp + ((long)b_*3*512 + (2*(oy+r)+1))*512 + ox;
      float4 rr = *(const float4*)&xb[0];
      float4 gg = *(const float4*)&xb[262144];
      float4 bb = *(const float4*)&xb[524288];
      iov[r] = make_float4(m0*rr.x + m1*gg.x + m2*bb.x,
                           m0*rr.y + m1*gg.y + m2*bb.y,
                           m0*rr.z + m1*gg.z + m2*bb.z,
                           m0*rr.w + m1*gg.w + m2*bb.w);
    }
  } else if (MODE == 1) {
    const float* s = Lw + (long)n*HW;
#pragma unroll
    for (int r = 0; r < 4; ++r) iov[r] = *(const float4*)&s[(oy+r)*IW + ox];
  } else {
    const float* s = (which ? Hw : Lw) + (long)n*(256*512);
#pragma unroll
    for (int r = 0; r < 4; ++r) {
      float4 a = *(const float4*)&s[(oy+r)*512 + 2*ox];
      float4 b = *(const float4*)&s[(oy+r)*512 + 2*ox + 4];
      iov[r] = (MODE == 2) ? make_float4(a.y, a.w, b.y, b.w)    // odd cols
                           : make_float4(a.x, a.z, b.x, b.z);   // even cols
    }
  }

  float* dst;
  if      (MODE == 0) dst = Hw + (long)n*HW;
  else if (MODE == 1) dst = Lw + (long)n*HW;
  else if (MODE == 2) dst = outp + (long)(b_*12 + (which?9:3) + c_)*65536;
  else                dst = outp + (long)(b_*12 + (which?6:0) + c_)*65536;

#pragma unroll
  for (int r = 0; r < 4; ++r) {
    float4 v;
    v.x = iov[r].x + sign * (ACCF[r][0] + b2);
    v.y = iov[r].y + sign * (ACCF[r][1] + b2);
    v.z = iov[r].z + sign * (ACCF[r][2] + b2);
    v.w = iov[r].w + sign * (ACCF[r][3] + b2);
    *(float4*)&dst[(oy + r)*IW + ox] = v;
  }
}

extern "C" void kernel_launch(void* const* d_in, const int* in_sizes, int n_in,
                              void* d_out, int out_size, void* d_ws, size_t ws_size,
                              hipStream_t stream) {
  const float* x   = (const float*)d_in[0];
  const float* Wp1 = (const float*)d_in[1];
  const float* bp1 = (const float*)d_in[2];
  const float* Wp2 = (const float*)d_in[3];
  const float* bp2 = (const float*)d_in[4];
  const float* Wu1 = (const float*)d_in[5];
  const float* bu1 = (const float*)d_in[6];
  const float* Wu2 = (const float*)d_in[7];
  const float* bu2 = (const float*)d_in[8];
  float* out = (float*)d_out;
  float* ws  = (float*)d_ws;

  // S1P: Hb' = Hb - p(L); materializes L
  k_subnet<0><<<dim3(8,4,24), 256, 0, stream>>>(x, ws, out, Wp1, bp1, Wp2, bp2);
  // S1U: L' = L + u(Hb')
  k_subnet<1><<<dim3(8,4,24), 256, 0, stream>>>(x, ws, out, Wu1, bu1, Wu2, bu2);
  // S2P: HL' = HL - pT(LL) -> q1 ; HH' = HH - pT(LH) -> q3
  k_subnet<2><<<dim3(4,4,48), 256, 0, stream>>>(x, ws, out, Wp1, bp1, Wp2, bp2);
  // S2U: LL' = LL + uT(HL') -> q0 ; LH' = LH + uT(HH') -> q2
  k_subnet<3><<<dim3(4,4,48), 256, 0, stream>>>(x, ws, out, Wu1, bu1, Wu2, bu2);
}